// Round 1
// baseline (859.111 us; speedup 1.0000x reference)
//
#include <hip/hip_runtime.h>
#include <math.h>

// ---------------------------------------------------------------------------
// 2-layer GCN: out = log_softmax( A' relu( A' (x W1) + b1 ) W2 + b2 )
// A' = D^-1/2 (A + I) D^-1/2, pull-style aggregation over CSR built per call.
// ---------------------------------------------------------------------------

__global__ void k_deg(const int* __restrict__ dst, int* __restrict__ deg, int E) {
    int e = blockIdx.x * blockDim.x + threadIdx.x;
    if (e < E) atomicAdd(&deg[dst[e]], 1);
}

__global__ void k_dinv(const int* __restrict__ deg, float* __restrict__ dinv, int N) {
    int i = blockIdx.x * blockDim.x + threadIdx.x;
    if (i < N) dinv[i] = rsqrtf((float)(deg[i] + 1));  // +1 = self loop; deg>=1 always
}

// Single-block exclusive scan over N=100k ints (1024 threads x ~98 chunk).
__global__ __launch_bounds__(1024) void k_scan(const int* __restrict__ deg,
                                               int* __restrict__ offsets, int n) {
    __shared__ int sums[1024];
    int tid = threadIdx.x;
    int chunk = (n + 1023) >> 10;
    int start = tid * chunk;
    int end = min(start + chunk, n);
    int s = 0;
    for (int i = start; i < end; ++i) s += deg[i];
    sums[tid] = s;
    __syncthreads();
    for (int off = 1; off < 1024; off <<= 1) {
        int v = (tid >= off) ? sums[tid - off] : 0;
        __syncthreads();
        sums[tid] += v;
        __syncthreads();
    }
    int excl = sums[tid] - s;  // exclusive prefix for this thread's chunk
    for (int i = start; i < end; ++i) { offsets[i] = excl; excl += deg[i]; }
    if (tid == 0) offsets[n] = sums[1023];
}

__global__ void k_fill(const int* __restrict__ src, const int* __restrict__ dst,
                       const int* __restrict__ offsets, int* __restrict__ cursor,
                       int* __restrict__ esrc, int E) {
    int e = blockIdx.x * blockDim.x + threadIdx.x;
    if (e < E) {
        int d = dst[e];
        int p = offsets[d] + atomicAdd(&cursor[d], 1);
        esrc[p] = src[e];
    }
}

// ---------------------------------------------------------------------------
// GEMM1: h0[M,128] = x[M,512] @ W[512,128].  fp32 VALU, 64x128 tile, BK=32.
// ---------------------------------------------------------------------------
#define BM 64
#define BN 128
#define BK 32

__global__ __launch_bounds__(256) void k_gemm1(const float* __restrict__ x,
                                               const float* __restrict__ W,
                                               float* __restrict__ h0, int M) {
    __shared__ float As[BK][BM];   // A stored transposed: As[k][row]
    __shared__ float Bs[BK][BN];
    int tid = threadIdx.x;
    int brow0 = blockIdx.x * BM;
    int tr = tid >> 5;             // 0..7  -> rows tr*8..tr*8+7
    int tc = tid & 31;             // 0..31 -> cols tc*4..tc*4+3
    float acc[8][4];
#pragma unroll
    for (int j = 0; j < 8; ++j)
#pragma unroll
        for (int c = 0; c < 4; ++c) acc[j][c] = 0.f;

    int arow = tid >> 2;           // 0..63
    int acol = (tid & 3) * 8;      // 0,8,16,24
    int brw  = tid >> 3;           // 0..31
    int bcl  = (tid & 7) * 16;     // 0..112

    for (int k0 = 0; k0 < 512; k0 += BK) {
        float4 a0 = make_float4(0.f, 0.f, 0.f, 0.f);
        float4 a1 = make_float4(0.f, 0.f, 0.f, 0.f);
        int gr = brow0 + arow;
        if (gr < M) {
            const float* xp = x + (size_t)gr * 512 + k0 + acol;
            a0 = *(const float4*)xp;
            a1 = *(const float4*)(xp + 4);
        }
        const float* wp = W + (size_t)(k0 + brw) * 128 + bcl;
        float4 b0 = *(const float4*)(wp + 0);
        float4 b1 = *(const float4*)(wp + 4);
        float4 b2 = *(const float4*)(wp + 8);
        float4 b3 = *(const float4*)(wp + 12);
        __syncthreads();           // previous iter's LDS reads done
        As[acol + 0][arow] = a0.x; As[acol + 1][arow] = a0.y;
        As[acol + 2][arow] = a0.z; As[acol + 3][arow] = a0.w;
        As[acol + 4][arow] = a1.x; As[acol + 5][arow] = a1.y;
        As[acol + 6][arow] = a1.z; As[acol + 7][arow] = a1.w;
        *(float4*)&Bs[brw][bcl + 0]  = b0;
        *(float4*)&Bs[brw][bcl + 4]  = b1;
        *(float4*)&Bs[brw][bcl + 8]  = b2;
        *(float4*)&Bs[brw][bcl + 12] = b3;
        __syncthreads();
#pragma unroll
        for (int kk = 0; kk < BK; ++kk) {
            float4 av0 = *(const float4*)&As[kk][tr * 8];
            float4 av1 = *(const float4*)&As[kk][tr * 8 + 4];
            float4 bv  = *(const float4*)&Bs[kk][tc * 4];
            float a[8] = {av0.x, av0.y, av0.z, av0.w, av1.x, av1.y, av1.z, av1.w};
            float b[4] = {bv.x, bv.y, bv.z, bv.w};
#pragma unroll
            for (int j = 0; j < 8; ++j)
#pragma unroll
                for (int c = 0; c < 4; ++c)
                    acc[j][c] = fmaf(a[j], b[c], acc[j][c]);
        }
    }
#pragma unroll
    for (int j = 0; j < 8; ++j) {
        int r = brow0 + tr * 8 + j;
        if (r < M) {
            float4 o = make_float4(acc[j][0], acc[j][1], acc[j][2], acc[j][3]);
            *(float4*)(h0 + (size_t)r * 128 + tc * 4) = o;
        }
    }
}

// ---------------------------------------------------------------------------
// Aggregation layer 1: one wave per node; lane covers 2 of 128 cols (float2).
// h1[i] = relu( dinv[i]^2*h0[i] + sum_e dinv[src]*dinv[i]*h0[src] + b1 )
// ---------------------------------------------------------------------------
__global__ __launch_bounds__(256) void k_agg1(const float* __restrict__ h0,
                                              const float* __restrict__ dinv,
                                              const int* __restrict__ offsets,
                                              const int* __restrict__ esrc,
                                              const float* __restrict__ b1,
                                              float* __restrict__ h1, int N) {
    int wid = (blockIdx.x * 256 + threadIdx.x) >> 6;
    if (wid >= N) return;
    int lane = threadIdx.x & 63;
    float di = dinv[wid];
    float2 v = ((const float2*)(h0 + (size_t)wid * 128))[lane];
    float wself = di * di;
    float2 acc = make_float2(wself * v.x, wself * v.y);
    int beg = offsets[wid], end = offsets[wid + 1];
    for (int e = beg; e < end; ++e) {
        int s = esrc[e];
        float w = dinv[s] * di;
        float2 u = ((const float2*)(h0 + (size_t)s * 128))[lane];
        acc.x = fmaf(w, u.x, acc.x);
        acc.y = fmaf(w, u.y, acc.y);
    }
    float2 bb = ((const float2*)b1)[lane];
    float2 o = make_float2(fmaxf(acc.x + bb.x, 0.f), fmaxf(acc.y + bb.y, 0.f));
    ((float2*)(h1 + (size_t)wid * 128))[lane] = o;
}

// ---------------------------------------------------------------------------
// GEMM2: h2[M,40] = h1[M,128] @ W2[128,40].  One row per thread, W2 in LDS.
// ---------------------------------------------------------------------------
__global__ __launch_bounds__(256) void k_gemm2(const float* __restrict__ h1,
                                               const float* __restrict__ W2,
                                               float* __restrict__ h2, int N) {
    __shared__ float w2s[128 * 40];
    int tid = threadIdx.x;
    for (int i = tid; i < 128 * 40; i += 256) w2s[i] = W2[i];
    __syncthreads();
    int r = blockIdx.x * 256 + tid;
    if (r >= N) return;
    const float4* row = (const float4*)(h1 + (size_t)r * 128);
    float acc[40];
#pragma unroll
    for (int c = 0; c < 40; ++c) acc[c] = 0.f;
    for (int k4 = 0; k4 < 32; ++k4) {
        float4 a = row[k4];
        float aa[4] = {a.x, a.y, a.z, a.w};
        int kb = k4 * 4;
#pragma unroll
        for (int kk = 0; kk < 4; ++kk) {
            float av = aa[kk];
            const float4* wr = (const float4*)&w2s[(kb + kk) * 40];
#pragma unroll
            for (int c4 = 0; c4 < 10; ++c4) {
                float4 w = wr[c4];
                acc[c4 * 4 + 0] = fmaf(av, w.x, acc[c4 * 4 + 0]);
                acc[c4 * 4 + 1] = fmaf(av, w.y, acc[c4 * 4 + 1]);
                acc[c4 * 4 + 2] = fmaf(av, w.z, acc[c4 * 4 + 2]);
                acc[c4 * 4 + 3] = fmaf(av, w.w, acc[c4 * 4 + 3]);
            }
        }
    }
    float* op = h2 + (size_t)r * 40;
#pragma unroll
    for (int c4 = 0; c4 < 10; ++c4)
        *(float4*)(op + c4 * 4) =
            make_float4(acc[c4 * 4], acc[c4 * 4 + 1], acc[c4 * 4 + 2], acc[c4 * 4 + 3]);
}

// ---------------------------------------------------------------------------
// Aggregation layer 2 + bias + log_softmax. One wave per node, lanes 0..39.
// ---------------------------------------------------------------------------
__global__ __launch_bounds__(256) void k_agg2(const float* __restrict__ h2,
                                              const float* __restrict__ dinv,
                                              const int* __restrict__ offsets,
                                              const int* __restrict__ esrc,
                                              const float* __restrict__ b2,
                                              float* __restrict__ out, int N) {
    int wid = (blockIdx.x * 256 + threadIdx.x) >> 6;
    if (wid >= N) return;
    int lane = threadIdx.x & 63;
    bool act = lane < 40;
    float di = dinv[wid];
    float v = act ? h2[(size_t)wid * 40 + lane] : 0.f;
    float acc = di * di * v;
    int beg = offsets[wid], end = offsets[wid + 1];
    for (int e = beg; e < end; ++e) {
        int s = esrc[e];
        float w = dinv[s] * di;
        float u = act ? h2[(size_t)s * 40 + lane] : 0.f;
        acc = fmaf(w, u, acc);
    }
    float logit = acc + (act ? b2[lane] : 0.f);
    float m = act ? logit : -1e30f;
#pragma unroll
    for (int o = 32; o > 0; o >>= 1) m = fmaxf(m, __shfl_xor(m, o));
    float pv = act ? __expf(logit - m) : 0.f;
    float ssum = pv;
#pragma unroll
    for (int o = 32; o > 0; o >>= 1) ssum += __shfl_xor(ssum, o);
    if (act) out[(size_t)wid * 40 + lane] = logit - m - __logf(ssum);
}

extern "C" void kernel_launch(void* const* d_in, const int* in_sizes, int n_in,
                              void* d_out, int out_size, void* d_ws, size_t ws_size,
                              hipStream_t stream) {
    const float* x  = (const float*)d_in[0];
    const int*   ei = (const int*)d_in[1];
    const float* W1 = (const float*)d_in[2];
    const float* b1 = (const float*)d_in[3];
    const float* W2 = (const float*)d_in[4];
    const float* b2 = (const float*)d_in[5];
    float* out = (float*)d_out;

    int N = in_sizes[0] / 512;
    int E = in_sizes[1] / 2;
    const int* esrc_in = ei;       // edge_index[0]
    const int* edst_in = ei + E;   // edge_index[1]

    // workspace layout (peak ~110 MB; h2 reuses h0 after agg1)
    char* p = (char*)d_ws;
    size_t off = 0;
    auto take = [&](size_t bytes) {
        size_t o = (off + 255) & ~(size_t)255;
        off = o + bytes;
        return (void*)(p + o);
    };
    float* h0   = (float*)take((size_t)N * 128 * 4);
    float* h1   = (float*)take((size_t)N * 128 * 4);
    int*   deg  = (int*)take((size_t)N * 4);
    float* dinv = (float*)take((size_t)N * 4);
    int*   offs = (int*)take((size_t)(N + 1) * 4);
    int*   cur  = (int*)take((size_t)N * 4);
    int*   esrc = (int*)take((size_t)E * 4);
    float* h2   = h0;  // h0 dead after k_agg1

    hipMemsetAsync(deg, 0, (size_t)N * 4, stream);
    hipMemsetAsync(cur, 0, (size_t)N * 4, stream);

    k_deg <<<(E + 255) / 256, 256, 0, stream>>>(edst_in, deg, E);
    k_scan<<<1, 1024, 0, stream>>>(deg, offs, N);
    k_dinv<<<(N + 255) / 256, 256, 0, stream>>>(deg, dinv, N);
    k_fill<<<(E + 255) / 256, 256, 0, stream>>>(esrc_in, edst_in, offs, cur, esrc, E);

    k_gemm1<<<(N + BM - 1) / BM, 256, 0, stream>>>(x, W1, h0, N);
    k_agg1 <<<(N + 3) / 4, 256, 0, stream>>>(h0, dinv, offs, esrc, b1, h1, N);
    k_gemm2<<<(N + 255) / 256, 256, 0, stream>>>(h1, W2, h2, N);
    k_agg2 <<<(N + 3) / 4, 256, 0, stream>>>(h2, dinv, offs, esrc, b2, out, N);
}

// Round 2
// 732.652 us; speedup vs baseline: 1.1726x; 1.1726x over previous
//
#include <hip/hip_runtime.h>
#include <math.h>

typedef __attribute__((ext_vector_type(8))) short short8v;
typedef __attribute__((ext_vector_type(4))) unsigned short ushort4v;
typedef __attribute__((ext_vector_type(8))) unsigned short ushort8v;
typedef __attribute__((ext_vector_type(4))) float f32x4;

__device__ inline unsigned short f2bf(float f) {  // RNE
    unsigned u = __float_as_uint(f);
    return (unsigned short)((u + 0x7fffu + ((u >> 16) & 1u)) >> 16);
}
__device__ inline float bflo(unsigned u) { return __uint_as_float(u << 16); }
__device__ inline float bfhi(unsigned u) { return __uint_as_float(u & 0xffff0000u); }

// ---------------------------------------------------------------------------
// CSR build
// ---------------------------------------------------------------------------
__global__ void k_deg(const int* __restrict__ dst, int* __restrict__ deg, int E) {
    int e = blockIdx.x * blockDim.x + threadIdx.x;
    if (e < E) atomicAdd(&deg[dst[e]], 1);
}

__global__ void k_dinv(const int* __restrict__ deg, float* __restrict__ dinv, int N) {
    int i = blockIdx.x * blockDim.x + threadIdx.x;
    if (i < N) dinv[i] = rsqrtf((float)(deg[i] + 1));  // +1 self loop
}

__global__ __launch_bounds__(1024) void k_scan(const int* __restrict__ deg,
                                               int* __restrict__ offsets, int n) {
    __shared__ int sums[1024];
    int tid = threadIdx.x;
    int chunk = (n + 1023) >> 10;
    int start = tid * chunk;
    int end = min(start + chunk, n);
    int s = 0;
    for (int i = start; i < end; ++i) s += deg[i];
    sums[tid] = s;
    __syncthreads();
    for (int off = 1; off < 1024; off <<= 1) {
        int v = (tid >= off) ? sums[tid - off] : 0;
        __syncthreads();
        sums[tid] += v;
        __syncthreads();
    }
    int excl = sums[tid] - s;
    for (int i = start; i < end; ++i) { offsets[i] = excl; excl += deg[i]; }
    if (tid == 0) offsets[n] = sums[1023];
}

__global__ void k_fill(const int* __restrict__ src, const int* __restrict__ dst,
                       const int* __restrict__ offsets, int* __restrict__ cursor,
                       int* __restrict__ esrc, int E) {
    int e = blockIdx.x * blockDim.x + threadIdx.x;
    if (e < E) {
        int d = dst[e];
        int p = offsets[d] + atomicAdd(&cursor[d], 1);
        esrc[p] = src[e];
    }
}

// ---------------------------------------------------------------------------
// W1 -> bf16, pre-swizzled into per-lane MFMA B-fragment order.
// Fragment: lane l, elem j: B[k = ks*32 + 8*(l>>4) + j][col = cb*16 + (l&15)]
// stored at Wswz[((ks*8+cb)*64 + l)*8 + j]
// ---------------------------------------------------------------------------
__global__ void k_wswz(const float* __restrict__ W1, unsigned short* __restrict__ Wswz) {
    int t = blockIdx.x * blockDim.x + threadIdx.x;
    if (t >= 16 * 8 * 64) return;
    int l = t & 63, cb = (t >> 6) & 7, ks = t >> 9;
    int col = cb * 16 + (l & 15);
    int kb = ks * 32 + 8 * (l >> 4);
    ushort8v w;
#pragma unroll
    for (int j = 0; j < 8; ++j) w[j] = f2bf(W1[(size_t)(kb + j) * 128 + col]);
    *(ushort8v*)(Wswz + (size_t)t * 8) = w;
}

// ---------------------------------------------------------------------------
// GEMM1: h0[M,128](bf16) = x[M,512](f32) @ W1(bf16 swizzled).
// 128x128 tile, BK=32, 4 waves in 2x2, mfma_f32_16x16x32_bf16.
// ---------------------------------------------------------------------------
#define GP 40   // As pitch (shorts): 80B rows -> 16B-aligned frags, ~2-way banks
#define CP 132  // Ct pitch (shorts): 264B rows -> g-groups 8 banks apart

__global__ __launch_bounds__(256) void k_gemm1(const float* __restrict__ x,
                                               const unsigned short* __restrict__ Wswz,
                                               unsigned short* __restrict__ h0, int M) {
    __shared__ unsigned short lds[128 * CP];  // union: As (pitch GP) / Ct (pitch CP)
    unsigned short* As = lds;
    int tid = threadIdx.x;
    int wid = tid >> 6, lane = tid & 63;
    int wr = wid >> 1, wc = wid & 1;
    int g = lane >> 4, lr = lane & 15;
    int brow = blockIdx.x * 128;

    f32x4 acc[4][4];
#pragma unroll
    for (int m = 0; m < 4; ++m)
#pragma unroll
        for (int n = 0; n < 4; ++n) acc[m][n] = (f32x4){0.f, 0.f, 0.f, 0.f};

    for (int k0 = 0; k0 < 512; k0 += 32) {
        float4 st[4];
#pragma unroll
        for (int i = 0; i < 4; ++i) {
            int idx = tid + 256 * i;
            int row = idx >> 3, q = idx & 7;
            int gr = brow + row;
            st[i] = (gr < M) ? *(const float4*)(x + (size_t)gr * 512 + k0 + q * 4)
                             : make_float4(0.f, 0.f, 0.f, 0.f);
        }
        __syncthreads();  // previous iter's frag reads done
#pragma unroll
        for (int i = 0; i < 4; ++i) {
            int idx = tid + 256 * i;
            int row = idx >> 3, q = idx & 7;
            ushort4v w;
            w[0] = f2bf(st[i].x); w[1] = f2bf(st[i].y);
            w[2] = f2bf(st[i].z); w[3] = f2bf(st[i].w);
            *(ushort4v*)&As[row * GP + q * 4] = w;
        }
        __syncthreads();
        int ks = k0 >> 5;
        short8v bfr[4];
#pragma unroll
        for (int n = 0; n < 4; ++n) {
            int cb = wc * 4 + n;
            bfr[n] = *(const short8v*)(Wswz + (size_t)((ks * 8 + cb) * 64 + lane) * 8);
        }
        short8v afr[4];
#pragma unroll
        for (int m = 0; m < 4; ++m) {
            int row = wr * 64 + m * 16 + lr;
            afr[m] = *(const short8v*)&As[row * GP + g * 8];
        }
#pragma unroll
        for (int m = 0; m < 4; ++m)
#pragma unroll
            for (int n = 0; n < 4; ++n)
                acc[m][n] = __builtin_amdgcn_mfma_f32_16x16x32_bf16(afr[m], bfr[n],
                                                                    acc[m][n], 0, 0, 0);
    }
    __syncthreads();  // done with As
    // C/D: col = l&15, row = 4*(l>>4)+reg  -> bf16 transpose staging in LDS
#pragma unroll
    for (int m = 0; m < 4; ++m) {
        int row0 = wr * 64 + m * 16 + g * 4;
#pragma unroll
        for (int n = 0; n < 4; ++n) {
            int col = wc * 64 + n * 16 + lr;
#pragma unroll
            for (int r = 0; r < 4; ++r)
                lds[(row0 + r) * CP + col] = f2bf(acc[m][n][r]);
        }
    }
    __syncthreads();
    {
        int row = tid >> 1, half = tid & 1;
        int gr = brow + row;
        if (gr < M) {
            unsigned short* dst = h0 + (size_t)gr * 128 + half * 64;
            const unsigned short* src = &lds[row * CP + half * 64];
#pragma unroll
            for (int i = 0; i < 16; ++i)
                *(ushort4v*)(dst + i * 4) = *(const ushort4v*)(src + i * 4);
        }
    }
}

// ---------------------------------------------------------------------------
// Aggregation 1: bf16 h0 gather, fp32 accum, +bias, relu -> h1 (fp32).
// ---------------------------------------------------------------------------
__global__ __launch_bounds__(256) void k_agg1(const unsigned short* __restrict__ h0,
                                              const float* __restrict__ dinv,
                                              const int* __restrict__ offsets,
                                              const int* __restrict__ esrc,
                                              const float* __restrict__ b1,
                                              float* __restrict__ h1, int N) {
    int wid = (blockIdx.x * 256 + threadIdx.x) >> 6;
    if (wid >= N) return;
    int lane = threadIdx.x & 63;
    float di = dinv[wid];
    unsigned u = ((const unsigned*)(h0 + (size_t)wid * 128))[lane];
    float wself = di * di;
    float ax = wself * bflo(u), ay = wself * bfhi(u);
    int beg = offsets[wid], end = offsets[wid + 1];
    for (int e = beg; e < end; ++e) {
        int s = esrc[e];
        float w = dinv[s] * di;
        unsigned v = ((const unsigned*)(h0 + (size_t)s * 128))[lane];
        ax = fmaf(w, bflo(v), ax);
        ay = fmaf(w, bfhi(v), ay);
    }
    float2 bb = ((const float2*)b1)[lane];
    ((float2*)(h1 + (size_t)wid * 128))[lane] =
        make_float2(fmaxf(ax + bb.x, 0.f), fmaxf(ay + bb.y, 0.f));
}

// ---------------------------------------------------------------------------
// GEMM2: h2[M,40](bf16) = h1[M,128](f32) @ W2[128,40](f32). Row per thread.
// ---------------------------------------------------------------------------
__global__ __launch_bounds__(256) void k_gemm2(const float* __restrict__ h1,
                                               const float* __restrict__ W2,
                                               unsigned short* __restrict__ h2, int N) {
    __shared__ float w2s[128 * 40];
    int tid = threadIdx.x;
    for (int i = tid; i < 128 * 40; i += 256) w2s[i] = W2[i];
    __syncthreads();
    int r = blockIdx.x * 256 + tid;
    if (r >= N) return;
    const float4* row = (const float4*)(h1 + (size_t)r * 128);
    float acc[40];
#pragma unroll
    for (int c = 0; c < 40; ++c) acc[c] = 0.f;
    for (int k4 = 0; k4 < 32; ++k4) {
        float4 a = row[k4];
        float aa[4] = {a.x, a.y, a.z, a.w};
        int kb = k4 * 4;
#pragma unroll
        for (int kk = 0; kk < 4; ++kk) {
            float av = aa[kk];
            const float4* wr = (const float4*)&w2s[(kb + kk) * 40];
#pragma unroll
            for (int c4 = 0; c4 < 10; ++c4) {
                float4 w = wr[c4];
                acc[c4 * 4 + 0] = fmaf(av, w.x, acc[c4 * 4 + 0]);
                acc[c4 * 4 + 1] = fmaf(av, w.y, acc[c4 * 4 + 1]);
                acc[c4 * 4 + 2] = fmaf(av, w.z, acc[c4 * 4 + 2]);
                acc[c4 * 4 + 3] = fmaf(av, w.w, acc[c4 * 4 + 3]);
            }
        }
    }
    unsigned short* op = h2 + (size_t)r * 40;
#pragma unroll
    for (int c4 = 0; c4 < 10; ++c4) {
        ushort4v w;
        w[0] = f2bf(acc[c4 * 4 + 0]); w[1] = f2bf(acc[c4 * 4 + 1]);
        w[2] = f2bf(acc[c4 * 4 + 2]); w[3] = f2bf(acc[c4 * 4 + 3]);
        *(ushort4v*)(op + c4 * 4) = w;
    }
}

// ---------------------------------------------------------------------------
// Aggregation 2 (bf16 h2 gather) + bias + log_softmax.
// ---------------------------------------------------------------------------
__global__ __launch_bounds__(256) void k_agg2(const unsigned short* __restrict__ h2,
                                              const float* __restrict__ dinv,
                                              const int* __restrict__ offsets,
                                              const int* __restrict__ esrc,
                                              const float* __restrict__ b2,
                                              float* __restrict__ out, int N) {
    int wid = (blockIdx.x * 256 + threadIdx.x) >> 6;
    if (wid >= N) return;
    int lane = threadIdx.x & 63;
    bool act = lane < 40;
    float di = dinv[wid];
    float v = act ? __uint_as_float((unsigned)h2[(size_t)wid * 40 + lane] << 16) : 0.f;
    float acc = di * di * v;
    int beg = offsets[wid], end = offsets[wid + 1];
    for (int e = beg; e < end; ++e) {
        int s = esrc[e];
        float w = dinv[s] * di;
        float u = act ? __uint_as_float((unsigned)h2[(size_t)s * 40 + lane] << 16) : 0.f;
        acc = fmaf(w, u, acc);
    }
    float logit = acc + (act ? b2[lane] : 0.f);
    float m = act ? logit : -1e30f;
#pragma unroll
    for (int o = 32; o > 0; o >>= 1) m = fmaxf(m, __shfl_xor(m, o));
    float pv = act ? __expf(logit - m) : 0.f;
    float ssum = pv;
#pragma unroll
    for (int o = 32; o > 0; o >>= 1) ssum += __shfl_xor(ssum, o);
    if (act) out[(size_t)wid * 40 + lane] = logit - m - __logf(ssum);
}

extern "C" void kernel_launch(void* const* d_in, const int* in_sizes, int n_in,
                              void* d_out, int out_size, void* d_ws, size_t ws_size,
                              hipStream_t stream) {
    const float* x  = (const float*)d_in[0];
    const int*   ei = (const int*)d_in[1];
    const float* W1 = (const float*)d_in[2];
    const float* b1 = (const float*)d_in[3];
    const float* W2 = (const float*)d_in[4];
    const float* b2 = (const float*)d_in[5];
    float* out = (float*)d_out;

    int N = in_sizes[0] / 512;
    int E = in_sizes[1] / 2;
    const int* esrc_in = ei;
    const int* edst_in = ei + E;

    char* p = (char*)d_ws;
    size_t off = 0;
    auto take = [&](size_t bytes) {
        size_t o = (off + 255) & ~(size_t)255;
        off = o + bytes;
        return (void*)(p + o);
    };
    unsigned short* h0   = (unsigned short*)take((size_t)N * 128 * 2);  // bf16
    float*          h1   = (float*)take((size_t)N * 128 * 4);
    unsigned short* wswz = (unsigned short*)take((size_t)16 * 8 * 64 * 8 * 2);
    int*   deg  = (int*)take((size_t)N * 4);
    float* dinv = (float*)take((size_t)N * 4);
    int*   offs = (int*)take((size_t)(N + 1) * 4);
    int*   cur  = (int*)take((size_t)N * 4);
    int*   esrc = (int*)take((size_t)E * 4);
    unsigned short* h2 = h0;  // h0 dead after k_agg1

    hipMemsetAsync(deg, 0, (size_t)N * 4, stream);
    hipMemsetAsync(cur, 0, (size_t)N * 4, stream);

    k_wswz<<<32, 256, 0, stream>>>(W1, wswz);
    k_deg <<<(E + 255) / 256, 256, 0, stream>>>(edst_in, deg, E);
    k_scan<<<1, 1024, 0, stream>>>(deg, offs, N);
    k_dinv<<<(N + 255) / 256, 256, 0, stream>>>(deg, dinv, N);
    k_fill<<<(E + 255) / 256, 256, 0, stream>>>(esrc_in, edst_in, offs, cur, esrc, E);

    k_gemm1<<<(N + 127) / 128, 256, 0, stream>>>(x, wswz, h0, N);
    k_agg1 <<<(N + 3) / 4, 256, 0, stream>>>(h0, dinv, offs, esrc, b1, h1, N);
    k_gemm2<<<(N + 255) / 256, 256, 0, stream>>>(h1, W2, h2, N);
    k_agg2 <<<(N + 3) / 4, 256, 0, stream>>>(h2, dinv, offs, esrc, b2, out, N);
}

// Round 3
// 581.748 us; speedup vs baseline: 1.4768x; 1.2594x over previous
//
#include <hip/hip_runtime.h>
#include <math.h>

typedef __attribute__((ext_vector_type(8))) short short8v;
typedef __attribute__((ext_vector_type(4))) unsigned short ushort4v;
typedef __attribute__((ext_vector_type(8))) unsigned short ushort8v;
typedef __attribute__((ext_vector_type(4))) float f32x4;

__device__ inline unsigned short f2bf(float f) {  // RNE
    unsigned u = __float_as_uint(f);
    return (unsigned short)((u + 0x7fffu + ((u >> 16) & 1u)) >> 16);
}
__device__ inline float bflo(unsigned u) { return __uint_as_float(u << 16); }
__device__ inline float bfhi(unsigned u) { return __uint_as_float(u & 0xffff0000u); }
__device__ inline float bf1(unsigned short s) { return __uint_as_float((unsigned)s << 16); }

// ---------------------------------------------------------------------------
// CSR build
// ---------------------------------------------------------------------------
__global__ void k_deg(const int* __restrict__ dst, int* __restrict__ deg, int E) {
    int e = blockIdx.x * blockDim.x + threadIdx.x;
    if (e < E) atomicAdd(&deg[dst[e]], 1);
}

__global__ void k_dinv(const int* __restrict__ deg, float* __restrict__ dinv, int N) {
    int i = blockIdx.x * blockDim.x + threadIdx.x;
    if (i < N) dinv[i] = rsqrtf((float)(deg[i] + 1));  // +1 self loop
}

__global__ __launch_bounds__(1024) void k_scan(const int* __restrict__ deg,
                                               int* __restrict__ offsets, int n) {
    __shared__ int sums[1024];
    int tid = threadIdx.x;
    int chunk = (n + 1023) >> 10;
    int start = tid * chunk;
    int end = min(start + chunk, n);
    int s = 0;
    for (int i = start; i < end; ++i) s += deg[i];
    sums[tid] = s;
    __syncthreads();
    for (int off = 1; off < 1024; off <<= 1) {
        int v = (tid >= off) ? sums[tid - off] : 0;
        __syncthreads();
        sums[tid] += v;
        __syncthreads();
    }
    int excl = sums[tid] - s;
    for (int i = start; i < end; ++i) { offsets[i] = excl; excl += deg[i]; }
    if (tid == 0) offsets[n] = sums[1023];
}

__global__ void k_fill(const int* __restrict__ src, const int* __restrict__ dst,
                       const int* __restrict__ offsets, int* __restrict__ cursor,
                       int* __restrict__ esrc, int E) {
    int e = blockIdx.x * blockDim.x + threadIdx.x;
    if (e < E) {
        int d = dst[e];
        int p = offsets[d] + atomicAdd(&cursor[d], 1);
        esrc[p] = src[e];
    }
}

// ---------------------------------------------------------------------------
// W1 -> bf16, pre-swizzled into per-lane MFMA B-fragment order.
// ---------------------------------------------------------------------------
__global__ void k_wswz(const float* __restrict__ W1, unsigned short* __restrict__ Wswz) {
    int t = blockIdx.x * blockDim.x + threadIdx.x;
    if (t >= 16 * 8 * 64) return;
    int l = t & 63, cb = (t >> 6) & 7, ks = t >> 9;
    int col = cb * 16 + (l & 15);
    int kb = ks * 32 + 8 * (l >> 4);
    ushort8v w;
#pragma unroll
    for (int j = 0; j < 8; ++j) w[j] = f2bf(W1[(size_t)(kb + j) * 128 + col]);
    *(ushort8v*)(Wswz + (size_t)t * 8) = w;
}

// ---------------------------------------------------------------------------
// GEMM1: h0s[M,128](bf16) = dinv[i] * (x[i,:] @ W1)  -- row-prescaled output.
// 128x128 tile, BK=32, 4 waves 2x2, mfma_f32_16x16x32_bf16.
// ---------------------------------------------------------------------------
#define GP 40   // As pitch (shorts)
#define CP 132  // Ct pitch (shorts)

__global__ __launch_bounds__(256) void k_gemm1(const float* __restrict__ x,
                                               const unsigned short* __restrict__ Wswz,
                                               const float* __restrict__ dinv,
                                               unsigned short* __restrict__ h0s, int M) {
    __shared__ unsigned short lds[128 * CP];
    unsigned short* As = lds;
    int tid = threadIdx.x;
    int wid = tid >> 6, lane = tid & 63;
    int wr = wid >> 1, wc = wid & 1;
    int g = lane >> 4, lr = lane & 15;
    int brow = blockIdx.x * 128;

    f32x4 acc[4][4];
#pragma unroll
    for (int m = 0; m < 4; ++m)
#pragma unroll
        for (int n = 0; n < 4; ++n) acc[m][n] = (f32x4){0.f, 0.f, 0.f, 0.f};

    for (int k0 = 0; k0 < 512; k0 += 32) {
        float4 st[4];
#pragma unroll
        for (int i = 0; i < 4; ++i) {
            int idx = tid + 256 * i;
            int row = idx >> 3, q = idx & 7;
            int gr = brow + row;
            st[i] = (gr < M) ? *(const float4*)(x + (size_t)gr * 512 + k0 + q * 4)
                             : make_float4(0.f, 0.f, 0.f, 0.f);
        }
        __syncthreads();
#pragma unroll
        for (int i = 0; i < 4; ++i) {
            int idx = tid + 256 * i;
            int row = idx >> 3, q = idx & 7;
            ushort4v w;
            w[0] = f2bf(st[i].x); w[1] = f2bf(st[i].y);
            w[2] = f2bf(st[i].z); w[3] = f2bf(st[i].w);
            *(ushort4v*)&As[row * GP + q * 4] = w;
        }
        __syncthreads();
        int ks = k0 >> 5;
        short8v bfr[4];
#pragma unroll
        for (int n = 0; n < 4; ++n) {
            int cb = wc * 4 + n;
            bfr[n] = *(const short8v*)(Wswz + (size_t)((ks * 8 + cb) * 64 + lane) * 8);
        }
        short8v afr[4];
#pragma unroll
        for (int m = 0; m < 4; ++m) {
            int row = wr * 64 + m * 16 + lr;
            afr[m] = *(const short8v*)&As[row * GP + g * 8];
        }
#pragma unroll
        for (int m = 0; m < 4; ++m)
#pragma unroll
            for (int n = 0; n < 4; ++n)
                acc[m][n] = __builtin_amdgcn_mfma_f32_16x16x32_bf16(afr[m], bfr[n],
                                                                    acc[m][n], 0, 0, 0);
    }
    __syncthreads();
    // C/D: col = l&15, row = 4*(l>>4)+reg ; scale by dinv[row] then bf16-stage
#pragma unroll
    for (int m = 0; m < 4; ++m) {
        int row0 = wr * 64 + m * 16 + g * 4;
        float dv[4];
#pragma unroll
        for (int r = 0; r < 4; ++r) {
            int gr = brow + row0 + r;
            dv[r] = (gr < M) ? dinv[gr] : 0.f;
        }
#pragma unroll
        for (int n = 0; n < 4; ++n) {
            int col = wc * 64 + n * 16 + lr;
#pragma unroll
            for (int r = 0; r < 4; ++r)
                lds[(row0 + r) * CP + col] = f2bf(acc[m][n][r] * dv[r]);
        }
    }
    __syncthreads();
    {
        int row = tid >> 1, half = tid & 1;
        int gr = brow + row;
        if (gr < M) {
            unsigned short* dst = h0s + (size_t)gr * 128 + half * 64;
            const unsigned short* src = &lds[row * CP + half * 64];
#pragma unroll
            for (int i = 0; i < 16; ++i)
                *(ushort4v*)(dst + i * 4) = *(const ushort4v*)(src + i * 4);
        }
    }
}

// ---------------------------------------------------------------------------
// Aggregation 1: h1[i] = relu( dinv[i] * (h0s[i] + sum_e h0s[src]) + b1 )
// One wave per node. Coalesced index prefetch + shfl broadcast, 4x unrolled
// independent row gathers (bf16, 4B/lane), fp32 accum.
// ---------------------------------------------------------------------------
__global__ __launch_bounds__(256) void k_agg1(const unsigned short* __restrict__ h0s,
                                              const float* __restrict__ dinv,
                                              const int* __restrict__ offsets,
                                              const int* __restrict__ esrc,
                                              const float* __restrict__ b1,
                                              float* __restrict__ h1, int N) {
    int wid = (blockIdx.x * 256 + threadIdx.x) >> 6;
    if (wid >= N) return;
    int lane = threadIdx.x & 63;
    const unsigned* base = (const unsigned*)h0s;  // row i = base + i*64
    unsigned us = base[(size_t)wid * 64 + lane];
    float ax = bflo(us), ay = bfhi(us);           // self term (prescaled)
    int beg = offsets[wid], end = offsets[wid + 1];
    for (int b0 = beg; b0 < end; b0 += 64) {
        int nb = min(64, end - b0);
        int idx = (lane < nb) ? esrc[b0 + lane] : 0;
        int k = 0;
        for (; k + 4 <= nb; k += 4) {
            int s0 = __shfl(idx, k + 0), s1 = __shfl(idx, k + 1);
            int s2 = __shfl(idx, k + 2), s3 = __shfl(idx, k + 3);
            unsigned v0 = base[(size_t)s0 * 64 + lane];
            unsigned v1 = base[(size_t)s1 * 64 + lane];
            unsigned v2 = base[(size_t)s2 * 64 + lane];
            unsigned v3 = base[(size_t)s3 * 64 + lane];
            ax += (bflo(v0) + bflo(v1)) + (bflo(v2) + bflo(v3));
            ay += (bfhi(v0) + bfhi(v1)) + (bfhi(v2) + bfhi(v3));
        }
        for (; k < nb; ++k) {
            int s = __shfl(idx, k);
            unsigned v = base[(size_t)s * 64 + lane];
            ax += bflo(v);
            ay += bfhi(v);
        }
    }
    float di = dinv[wid];
    float2 bb = ((const float2*)b1)[lane];
    ((float2*)(h1 + (size_t)wid * 128))[lane] =
        make_float2(fmaxf(fmaf(di, ax, bb.x), 0.f), fmaxf(fmaf(di, ay, bb.y), 0.f));
}

// ---------------------------------------------------------------------------
// GEMM2: h2s[M,40](bf16) = dinv[r] * (h1[r,:] @ W2). Row per thread, W2 in LDS.
// ---------------------------------------------------------------------------
__global__ __launch_bounds__(256) void k_gemm2(const float* __restrict__ h1,
                                               const float* __restrict__ W2,
                                               const float* __restrict__ dinv,
                                               unsigned short* __restrict__ h2s, int N) {
    __shared__ float w2s[128 * 40];
    int tid = threadIdx.x;
    for (int i = tid; i < 128 * 40; i += 256) w2s[i] = W2[i];
    __syncthreads();
    int r = blockIdx.x * 256 + tid;
    if (r >= N) return;
    const float4* row = (const float4*)(h1 + (size_t)r * 128);
    float acc[40];
#pragma unroll
    for (int c = 0; c < 40; ++c) acc[c] = 0.f;
    for (int k4 = 0; k4 < 32; ++k4) {
        float4 a = row[k4];
        float aa[4] = {a.x, a.y, a.z, a.w};
        int kb = k4 * 4;
#pragma unroll
        for (int kk = 0; kk < 4; ++kk) {
            float av = aa[kk];
            const float4* wr = (const float4*)&w2s[(kb + kk) * 40];
#pragma unroll
            for (int c4 = 0; c4 < 10; ++c4) {
                float4 w = wr[c4];
                acc[c4 * 4 + 0] = fmaf(av, w.x, acc[c4 * 4 + 0]);
                acc[c4 * 4 + 1] = fmaf(av, w.y, acc[c4 * 4 + 1]);
                acc[c4 * 4 + 2] = fmaf(av, w.z, acc[c4 * 4 + 2]);
                acc[c4 * 4 + 3] = fmaf(av, w.w, acc[c4 * 4 + 3]);
            }
        }
    }
    float di = dinv[r];
    unsigned short* op = h2s + (size_t)r * 40;
#pragma unroll
    for (int c4 = 0; c4 < 10; ++c4) {
        ushort4v w;
        w[0] = f2bf(acc[c4 * 4 + 0] * di); w[1] = f2bf(acc[c4 * 4 + 1] * di);
        w[2] = f2bf(acc[c4 * 4 + 2] * di); w[3] = f2bf(acc[c4 * 4 + 3] * di);
        *(ushort4v*)(op + c4 * 4) = w;
    }
}

// ---------------------------------------------------------------------------
// Aggregation 2 + bias + log_softmax.
// logit = dinv[i]*(h2s[i] + sum_e h2s[src]) + b2
// ---------------------------------------------------------------------------
__global__ __launch_bounds__(256) void k_agg2(const unsigned short* __restrict__ h2s,
                                              const float* __restrict__ dinv,
                                              const int* __restrict__ offsets,
                                              const int* __restrict__ esrc,
                                              const float* __restrict__ b2,
                                              float* __restrict__ out, int N) {
    int wid = (blockIdx.x * 256 + threadIdx.x) >> 6;
    if (wid >= N) return;
    int lane = threadIdx.x & 63;
    bool act = lane < 40;
    float acc = act ? bf1(h2s[(size_t)wid * 40 + lane]) : 0.f;  // self (prescaled)
    int beg = offsets[wid], end = offsets[wid + 1];
    for (int b0 = beg; b0 < end; b0 += 64) {
        int nb = min(64, end - b0);
        int idx = (lane < nb) ? esrc[b0 + lane] : 0;
        int k = 0;
        for (; k + 4 <= nb; k += 4) {
            int s0 = __shfl(idx, k + 0), s1 = __shfl(idx, k + 1);
            int s2 = __shfl(idx, k + 2), s3 = __shfl(idx, k + 3);
            float u0 = act ? bf1(h2s[(size_t)s0 * 40 + lane]) : 0.f;
            float u1 = act ? bf1(h2s[(size_t)s1 * 40 + lane]) : 0.f;
            float u2 = act ? bf1(h2s[(size_t)s2 * 40 + lane]) : 0.f;
            float u3 = act ? bf1(h2s[(size_t)s3 * 40 + lane]) : 0.f;
            acc += (u0 + u1) + (u2 + u3);
        }
        for (; k < nb; ++k) {
            int s = __shfl(idx, k);
            acc += act ? bf1(h2s[(size_t)s * 40 + lane]) : 0.f;
        }
    }
    float di = dinv[wid];
    float logit = fmaf(di, acc, act ? b2[lane] : 0.f);
    float m = act ? logit : -1e30f;
#pragma unroll
    for (int o = 32; o > 0; o >>= 1) m = fmaxf(m, __shfl_xor(m, o));
    float pv = act ? __expf(logit - m) : 0.f;
    float ssum = pv;
#pragma unroll
    for (int o = 32; o > 0; o >>= 1) ssum += __shfl_xor(ssum, o);
    if (act) out[(size_t)wid * 40 + lane] = logit - m - __logf(ssum);
}

extern "C" void kernel_launch(void* const* d_in, const int* in_sizes, int n_in,
                              void* d_out, int out_size, void* d_ws, size_t ws_size,
                              hipStream_t stream) {
    const float* x  = (const float*)d_in[0];
    const int*   ei = (const int*)d_in[1];
    const float* W1 = (const float*)d_in[2];
    const float* b1 = (const float*)d_in[3];
    const float* W2 = (const float*)d_in[4];
    const float* b2 = (const float*)d_in[5];
    float* out = (float*)d_out;

    int N = in_sizes[0] / 512;
    int E = in_sizes[1] / 2;
    const int* esrc_in = ei;
    const int* edst_in = ei + E;

    char* p = (char*)d_ws;
    size_t off = 0;
    auto take = [&](size_t bytes) {
        size_t o = (off + 255) & ~(size_t)255;
        off = o + bytes;
        return (void*)(p + o);
    };
    unsigned short* h0s  = (unsigned short*)take((size_t)N * 128 * 2);  // bf16 prescaled
    float*          h1   = (float*)take((size_t)N * 128 * 4);
    unsigned short* wswz = (unsigned short*)take((size_t)16 * 8 * 64 * 8 * 2);
    int*   deg  = (int*)take((size_t)N * 4);
    float* dinv = (float*)take((size_t)N * 4);
    int*   offs = (int*)take((size_t)(N + 1) * 4);
    int*   cur  = (int*)take((size_t)N * 4);
    int*   esrc = (int*)take((size_t)E * 4);
    unsigned short* h2s = h0s;  // h0s dead after k_agg1

    hipMemsetAsync(deg, 0, (size_t)N * 4, stream);
    hipMemsetAsync(cur, 0, (size_t)N * 4, stream);

    k_wswz<<<32, 256, 0, stream>>>(W1, wswz);
    k_deg <<<(E + 255) / 256, 256, 0, stream>>>(edst_in, deg, E);
    k_scan<<<1, 1024, 0, stream>>>(deg, offs, N);
    k_dinv<<<(N + 255) / 256, 256, 0, stream>>>(deg, dinv, N);
    k_fill<<<(E + 255) / 256, 256, 0, stream>>>(esrc_in, edst_in, offs, cur, esrc, E);

    k_gemm1<<<(N + 127) / 128, 256, 0, stream>>>(x, wswz, dinv, h0s, N);
    k_agg1 <<<(N + 3) / 4, 256, 0, stream>>>(h0s, dinv, offs, esrc, b1, h1, N);
    k_gemm2<<<(N + 255) / 256, 256, 0, stream>>>(h1, W2, dinv, h2s, N);
    k_agg2 <<<(N + 3) / 4, 256, 0, stream>>>(h2s, dinv, offs, esrc, b2, out, N);
}

// Round 4
// 433.605 us; speedup vs baseline: 1.9813x; 1.3417x over previous
//
#include <hip/hip_runtime.h>
#include <math.h>

typedef __attribute__((ext_vector_type(8))) short short8v;
typedef __attribute__((ext_vector_type(4))) unsigned short ushort4v;
typedef __attribute__((ext_vector_type(8))) unsigned short ushort8v;
typedef __attribute__((ext_vector_type(4))) float f32x4;

__device__ inline unsigned short f2bf(float f) {  // RNE
    unsigned u = __float_as_uint(f);
    return (unsigned short)((u + 0x7fffu + ((u >> 16) & 1u)) >> 16);
}
__device__ inline float bflo(unsigned u) { return __uint_as_float(u << 16); }
__device__ inline float bfhi(unsigned u) { return __uint_as_float(u & 0xffff0000u); }
__device__ inline float bf1(unsigned short s) { return __uint_as_float((unsigned)s << 16); }

// ---------------------------------------------------------------------------
// CSR build
// ---------------------------------------------------------------------------
__global__ void k_deg(const int* __restrict__ dst, int* __restrict__ deg, int E) {
    int e = blockIdx.x * blockDim.x + threadIdx.x;
    if (e < E) atomicAdd(&deg[dst[e]], 1);
}

__global__ void k_dinv(const int* __restrict__ deg, float* __restrict__ dinv, int N) {
    int i = blockIdx.x * blockDim.x + threadIdx.x;
    if (i < N) dinv[i] = rsqrtf((float)(deg[i] + 1));  // +1 self loop
}

// --- hierarchical exclusive scan: 1024-elem tiles ---------------------------
__global__ __launch_bounds__(256) void k_bsum(const int* __restrict__ deg,
                                              int* __restrict__ bsum, int n) {
    __shared__ int r[256];
    int b = blockIdx.x, tid = threadIdx.x;
    int i0 = b * 1024 + tid * 4;
    int s = 0;
#pragma unroll
    for (int j = 0; j < 4; ++j)
        if (i0 + j < n) s += deg[i0 + j];
    r[tid] = s;
    __syncthreads();
    for (int off = 128; off > 0; off >>= 1) {
        if (tid < off) r[tid] += r[tid + off];
        __syncthreads();
    }
    if (tid == 0) bsum[b] = r[0];
}

__global__ __launch_bounds__(1024) void k_scan2(const int* __restrict__ bsum,
                                                int* __restrict__ bpre,
                                                int* __restrict__ total_out, int nb) {
    __shared__ int ls[1024];
    int tid = threadIdx.x;
    int v = (tid < nb) ? bsum[tid] : 0;
    ls[tid] = v;
    __syncthreads();
    for (int off = 1; off < 1024; off <<= 1) {
        int t = (tid >= off) ? ls[tid - off] : 0;
        __syncthreads();
        ls[tid] += t;
        __syncthreads();
    }
    if (tid < nb) bpre[tid] = ls[tid] - v;
    if (tid == 1023) *total_out = ls[1023];
}

__global__ __launch_bounds__(256) void k_scan3(const int* __restrict__ deg,
                                               const int* __restrict__ bpre,
                                               int* __restrict__ offsets, int n) {
    __shared__ int ts[256];
    int b = blockIdx.x, tid = threadIdx.x;
    int i0 = b * 1024 + tid * 4;
    int v[4] = {0, 0, 0, 0};
#pragma unroll
    for (int j = 0; j < 4; ++j)
        if (i0 + j < n) v[j] = deg[i0 + j];
    int s = v[0] + v[1] + v[2] + v[3];
    ts[tid] = s;
    __syncthreads();
    for (int off = 1; off < 256; off <<= 1) {
        int t = (tid >= off) ? ts[tid - off] : 0;
        __syncthreads();
        ts[tid] += t;
        __syncthreads();
    }
    int excl = bpre[b] + ts[tid] - s;
#pragma unroll
    for (int j = 0; j < 4; ++j) {
        if (i0 + j < n) offsets[i0 + j] = excl;
        excl += v[j];
    }
}

__global__ void k_fill(const int* __restrict__ src, const int* __restrict__ dst,
                       const int* __restrict__ offsets, int* __restrict__ cursor,
                       int* __restrict__ esrc, int E) {
    int e = blockIdx.x * blockDim.x + threadIdx.x;
    if (e < E) {
        int d = dst[e];
        int p = offsets[d] + atomicAdd(&cursor[d], 1);
        esrc[p] = src[e];
    }
}

// ---------------------------------------------------------------------------
// W1 -> bf16, pre-swizzled into per-lane MFMA B-fragment order.
// ---------------------------------------------------------------------------
__global__ void k_wswz(const float* __restrict__ W1, unsigned short* __restrict__ Wswz) {
    int t = blockIdx.x * blockDim.x + threadIdx.x;
    if (t >= 16 * 8 * 64) return;
    int l = t & 63, cb = (t >> 6) & 7, ks = t >> 9;
    int col = cb * 16 + (l & 15);
    int kb = ks * 32 + 8 * (l >> 4);
    ushort8v w;
#pragma unroll
    for (int j = 0; j < 8; ++j) w[j] = f2bf(W1[(size_t)(kb + j) * 128 + col]);
    *(ushort8v*)(Wswz + (size_t)t * 8) = w;
}

// ---------------------------------------------------------------------------
// GEMM1: h0s[M,128](bf16) = dinv[i] * (x[i,:] @ W1)  -- row-prescaled output.
// 128x128 tile, BK=32, 4 waves 2x2, mfma_f32_16x16x32_bf16.
// ---------------------------------------------------------------------------
#define GP 40   // As pitch (shorts)
#define CP 132  // Ct pitch (shorts)

__global__ __launch_bounds__(256) void k_gemm1(const float* __restrict__ x,
                                               const unsigned short* __restrict__ Wswz,
                                               const float* __restrict__ dinv,
                                               unsigned short* __restrict__ h0s, int M) {
    __shared__ unsigned short lds[128 * CP];
    unsigned short* As = lds;
    int tid = threadIdx.x;
    int wid = tid >> 6, lane = tid & 63;
    int wr = wid >> 1, wc = wid & 1;
    int g = lane >> 4, lr = lane & 15;
    int brow = blockIdx.x * 128;

    f32x4 acc[4][4];
#pragma unroll
    for (int m = 0; m < 4; ++m)
#pragma unroll
        for (int n = 0; n < 4; ++n) acc[m][n] = (f32x4){0.f, 0.f, 0.f, 0.f};

    for (int k0 = 0; k0 < 512; k0 += 32) {
        float4 st[4];
#pragma unroll
        for (int i = 0; i < 4; ++i) {
            int idx = tid + 256 * i;
            int row = idx >> 3, q = idx & 7;
            int gr = brow + row;
            st[i] = (gr < M) ? *(const float4*)(x + (size_t)gr * 512 + k0 + q * 4)
                             : make_float4(0.f, 0.f, 0.f, 0.f);
        }
        __syncthreads();
#pragma unroll
        for (int i = 0; i < 4; ++i) {
            int idx = tid + 256 * i;
            int row = idx >> 3, q = idx & 7;
            ushort4v w;
            w[0] = f2bf(st[i].x); w[1] = f2bf(st[i].y);
            w[2] = f2bf(st[i].z); w[3] = f2bf(st[i].w);
            *(ushort4v*)&As[row * GP + q * 4] = w;
        }
        __syncthreads();
        int ks = k0 >> 5;
        short8v bfr[4];
#pragma unroll
        for (int n = 0; n < 4; ++n) {
            int cb = wc * 4 + n;
            bfr[n] = *(const short8v*)(Wswz + (size_t)((ks * 8 + cb) * 64 + lane) * 8);
        }
        short8v afr[4];
#pragma unroll
        for (int m = 0; m < 4; ++m) {
            int row = wr * 64 + m * 16 + lr;
            afr[m] = *(const short8v*)&As[row * GP + g * 8];
        }
#pragma unroll
        for (int m = 0; m < 4; ++m)
#pragma unroll
            for (int n = 0; n < 4; ++n)
                acc[m][n] = __builtin_amdgcn_mfma_f32_16x16x32_bf16(afr[m], bfr[n],
                                                                    acc[m][n], 0, 0, 0);
    }
    __syncthreads();
    // C/D: col = l&15, row = 4*(l>>4)+reg ; scale by dinv[row] then bf16-stage
#pragma unroll
    for (int m = 0; m < 4; ++m) {
        int row0 = wr * 64 + m * 16 + g * 4;
        float dv[4];
#pragma unroll
        for (int r = 0; r < 4; ++r) {
            int gr = brow + row0 + r;
            dv[r] = (gr < M) ? dinv[gr] : 0.f;
        }
#pragma unroll
        for (int n = 0; n < 4; ++n) {
            int col = wc * 64 + n * 16 + lr;
#pragma unroll
            for (int r = 0; r < 4; ++r)
                lds[(row0 + r) * CP + col] = f2bf(acc[m][n][r] * dv[r]);
        }
    }
    __syncthreads();
    {
        int row = tid >> 1, half = tid & 1;
        int gr = brow + row;
        if (gr < M) {
            unsigned short* dst = h0s + (size_t)gr * 128 + half * 64;
            const unsigned short* src = &lds[row * CP + half * 64];
#pragma unroll
            for (int i = 0; i < 16; ++i)
                *(ushort4v*)(dst + i * 4) = *(const ushort4v*)(src + i * 4);
        }
    }
}

// ---------------------------------------------------------------------------
// Aggregation 1: h1[i] = relu( dinv[i] * (h0s[i] + sum_e h0s[src]) + b1 )
// ---------------------------------------------------------------------------
__global__ __launch_bounds__(256) void k_agg1(const unsigned short* __restrict__ h0s,
                                              const float* __restrict__ dinv,
                                              const int* __restrict__ offsets,
                                              const int* __restrict__ esrc,
                                              const float* __restrict__ b1,
                                              float* __restrict__ h1, int N) {
    int wid = (blockIdx.x * 256 + threadIdx.x) >> 6;
    if (wid >= N) return;
    int lane = threadIdx.x & 63;
    const unsigned* base = (const unsigned*)h0s;  // row i = base + i*64
    unsigned us = base[(size_t)wid * 64 + lane];
    float ax = bflo(us), ay = bfhi(us);           // self term (prescaled)
    int beg = offsets[wid], end = offsets[wid + 1];
    for (int b0 = beg; b0 < end; b0 += 64) {
        int nb = min(64, end - b0);
        int idx = (lane < nb) ? esrc[b0 + lane] : 0;
        int k = 0;
        for (; k + 4 <= nb; k += 4) {
            int s0 = __shfl(idx, k + 0), s1 = __shfl(idx, k + 1);
            int s2 = __shfl(idx, k + 2), s3 = __shfl(idx, k + 3);
            unsigned v0 = base[(size_t)s0 * 64 + lane];
            unsigned v1 = base[(size_t)s1 * 64 + lane];
            unsigned v2 = base[(size_t)s2 * 64 + lane];
            unsigned v3 = base[(size_t)s3 * 64 + lane];
            ax += (bflo(v0) + bflo(v1)) + (bflo(v2) + bflo(v3));
            ay += (bfhi(v0) + bfhi(v1)) + (bfhi(v2) + bfhi(v3));
        }
        for (; k < nb; ++k) {
            int s = __shfl(idx, k);
            unsigned v = base[(size_t)s * 64 + lane];
            ax += bflo(v);
            ay += bfhi(v);
        }
    }
    float di = dinv[wid];
    float2 bb = ((const float2*)b1)[lane];
    ((float2*)(h1 + (size_t)wid * 128))[lane] =
        make_float2(fmaxf(fmaf(di, ax, bb.x), 0.f), fmaxf(fmaf(di, ay, bb.y), 0.f));
}

// ---------------------------------------------------------------------------
// GEMM2: h2s[M,40](bf16) = dinv[r] * (h1[r,:] @ W2). Row per thread, W2 in LDS.
// ---------------------------------------------------------------------------
__global__ __launch_bounds__(256) void k_gemm2(const float* __restrict__ h1,
                                               const float* __restrict__ W2,
                                               const float* __restrict__ dinv,
                                               unsigned short* __restrict__ h2s, int N) {
    __shared__ float w2s[128 * 40];
    int tid = threadIdx.x;
    for (int i = tid; i < 128 * 40; i += 256) w2s[i] = W2[i];
    __syncthreads();
    int r = blockIdx.x * 256 + tid;
    if (r >= N) return;
    const float4* row = (const float4*)(h1 + (size_t)r * 128);
    float acc[40];
#pragma unroll
    for (int c = 0; c < 40; ++c) acc[c] = 0.f;
    for (int k4 = 0; k4 < 32; ++k4) {
        float4 a = row[k4];
        float aa[4] = {a.x, a.y, a.z, a.w};
        int kb = k4 * 4;
#pragma unroll
        for (int kk = 0; kk < 4; ++kk) {
            float av = aa[kk];
            const float4* wr = (const float4*)&w2s[(kb + kk) * 40];
#pragma unroll
            for (int c4 = 0; c4 < 10; ++c4) {
                float4 w = wr[c4];
                acc[c4 * 4 + 0] = fmaf(av, w.x, acc[c4 * 4 + 0]);
                acc[c4 * 4 + 1] = fmaf(av, w.y, acc[c4 * 4 + 1]);
                acc[c4 * 4 + 2] = fmaf(av, w.z, acc[c4 * 4 + 2]);
                acc[c4 * 4 + 3] = fmaf(av, w.w, acc[c4 * 4 + 3]);
            }
        }
    }
    float di = dinv[r];
    unsigned short* op = h2s + (size_t)r * 40;
#pragma unroll
    for (int c4 = 0; c4 < 10; ++c4) {
        ushort4v w;
        w[0] = f2bf(acc[c4 * 4 + 0] * di); w[1] = f2bf(acc[c4 * 4 + 1] * di);
        w[2] = f2bf(acc[c4 * 4 + 2] * di); w[3] = f2bf(acc[c4 * 4 + 3] * di);
        *(ushort4v*)(op + c4 * 4) = w;
    }
}

// ---------------------------------------------------------------------------
// Aggregation 2 + bias + log_softmax.
// ---------------------------------------------------------------------------
__global__ __launch_bounds__(256) void k_agg2(const unsigned short* __restrict__ h2s,
                                              const float* __restrict__ dinv,
                                              const int* __restrict__ offsets,
                                              const int* __restrict__ esrc,
                                              const float* __restrict__ b2,
                                              float* __restrict__ out, int N) {
    int wid = (blockIdx.x * 256 + threadIdx.x) >> 6;
    if (wid >= N) return;
    int lane = threadIdx.x & 63;
    bool act = lane < 40;
    float acc = act ? bf1(h2s[(size_t)wid * 40 + lane]) : 0.f;  // self (prescaled)
    int beg = offsets[wid], end = offsets[wid + 1];
    for (int b0 = beg; b0 < end; b0 += 64) {
        int nb = min(64, end - b0);
        int idx = (lane < nb) ? esrc[b0 + lane] : 0;
        int k = 0;
        for (; k + 4 <= nb; k += 4) {
            int s0 = __shfl(idx, k + 0), s1 = __shfl(idx, k + 1);
            int s2 = __shfl(idx, k + 2), s3 = __shfl(idx, k + 3);
            float u0 = act ? bf1(h2s[(size_t)s0 * 40 + lane]) : 0.f;
            float u1 = act ? bf1(h2s[(size_t)s1 * 40 + lane]) : 0.f;
            float u2 = act ? bf1(h2s[(size_t)s2 * 40 + lane]) : 0.f;
            float u3 = act ? bf1(h2s[(size_t)s3 * 40 + lane]) : 0.f;
            acc += (u0 + u1) + (u2 + u3);
        }
        for (; k < nb; ++k) {
            int s = __shfl(idx, k);
            acc += act ? bf1(h2s[(size_t)s * 40 + lane]) : 0.f;
        }
    }
    float di = dinv[wid];
    float logit = fmaf(di, acc, act ? b2[lane] : 0.f);
    float m = act ? logit : -1e30f;
#pragma unroll
    for (int o = 32; o > 0; o >>= 1) m = fmaxf(m, __shfl_xor(m, o));
    float pv = act ? __expf(logit - m) : 0.f;
    float ssum = pv;
#pragma unroll
    for (int o = 32; o > 0; o >>= 1) ssum += __shfl_xor(ssum, o);
    if (act) out[(size_t)wid * 40 + lane] = logit - m - __logf(ssum);
}

extern "C" void kernel_launch(void* const* d_in, const int* in_sizes, int n_in,
                              void* d_out, int out_size, void* d_ws, size_t ws_size,
                              hipStream_t stream) {
    const float* x  = (const float*)d_in[0];
    const int*   ei = (const int*)d_in[1];
    const float* W1 = (const float*)d_in[2];
    const float* b1 = (const float*)d_in[3];
    const float* W2 = (const float*)d_in[4];
    const float* b2 = (const float*)d_in[5];
    float* out = (float*)d_out;

    int N = in_sizes[0] / 512;
    int E = in_sizes[1] / 2;
    const int* esrc_in = ei;
    const int* edst_in = ei + E;
    int nb = (N + 1023) / 1024;  // scan tiles

    char* p = (char*)d_ws;
    size_t off = 0;
    auto take = [&](size_t bytes) {
        size_t o = (off + 255) & ~(size_t)255;
        off = o + bytes;
        return (void*)(p + o);
    };
    unsigned short* h0s  = (unsigned short*)take((size_t)N * 128 * 2);  // bf16 prescaled
    float*          h1   = (float*)take((size_t)N * 128 * 4);
    unsigned short* wswz = (unsigned short*)take((size_t)16 * 8 * 64 * 8 * 2);
    int*   deg  = (int*)take((size_t)N * 4);
    float* dinv = (float*)take((size_t)N * 4);
    int*   offs = (int*)take((size_t)(N + 1) * 4);
    int*   cur  = (int*)take((size_t)N * 4);
    int*   bsum = (int*)take((size_t)nb * 4);
    int*   bpre = (int*)take((size_t)nb * 4);
    int*   esrc = (int*)take((size_t)E * 4);
    unsigned short* h2s = h0s;  // h0s dead after k_agg1

    hipMemsetAsync(deg, 0, (size_t)N * 4, stream);
    hipMemsetAsync(cur, 0, (size_t)N * 4, stream);

    k_wswz<<<32, 256, 0, stream>>>(W1, wswz);
    k_deg <<<(E + 255) / 256, 256, 0, stream>>>(edst_in, deg, E);
    k_bsum <<<nb, 256, 0, stream>>>(deg, bsum, N);
    k_scan2<<<1, 1024, 0, stream>>>(bsum, bpre, offs + N, nb);
    k_scan3<<<nb, 256, 0, stream>>>(deg, bpre, offs, N);
    k_dinv<<<(N + 255) / 256, 256, 0, stream>>>(deg, dinv, N);
    k_fill<<<(E + 255) / 256, 256, 0, stream>>>(esrc_in, edst_in, offs, cur, esrc, E);

    k_gemm1<<<(N + 127) / 128, 256, 0, stream>>>(x, wswz, dinv, h0s, N);
    k_agg1 <<<(N + 3) / 4, 256, 0, stream>>>(h0s, dinv, offs, esrc, b1, h1, N);
    k_gemm2<<<(N + 255) / 256, 256, 0, stream>>>(h1, W2, dinv, h2s, N);
    k_agg2 <<<(N + 3) / 4, 256, 0, stream>>>(h2s, dinv, offs, esrc, b2, out, N);
}